// Round 7
// baseline (101.869 us; speedup 1.0000x reference)
//
#include <hip/hip_runtime.h>

// VectorQuantiser R7: per-wave-latency attack.
//  prep: ecvt f16-split codebook [512][128], e2[512], embT_s[512][64]=(emb+mean)*sd.
//  main: 512 blocks x 256 thr (4 waves), zero-LDS A staging (64 rows/wave in 64 VGPR
//  of f16 frags built straight from global), double-buffered B prefetch from
//  L2-resident ecvt, 24 MFMA per 4-load batch, one barrier (kb exchange),
//  streaming epilogue from embT_s (no gather, no x re-read).
// dist = e2[k] - 2*(xh·eh + xh·el + xl·eh)  (x2 dropped: argmin-invariant;
// term-set validated R3-R6, absmax 1.2e-4, indices exact).

typedef _Float16 f16;
typedef _Float16 f16x8 __attribute__((ext_vector_type(8)));
typedef float    f32x4 __attribute__((ext_vector_type(4)));

#define NELEM0 8388608
#define FLTMAX 3.402823466e38f
// ws: [0,131072) ecvt f16[512][128]; [131072,133120) e2 f32[512];
//     [133120,264192) embT_s f32[512][64]
#define WS_NEED 264192

__global__ void prep_kernel(const float* __restrict__ emb, const float* __restrict__ meanp,
                            const float* __restrict__ sdp, f16* __restrict__ ecvt,
                            float* __restrict__ e2g, float* __restrict__ embt) {
    const int code = blockIdx.x * 256 + threadIdx.x;   // 512 total
    const float mean = meanp[0];
    const float sd   = sdp[0];
    float s = 0.0f;
    #pragma unroll 8
    for (int d = 0; d < 64; ++d) {
        float v = emb[d * 512 + code];                 // coalesced across codes
        s = fmaf(v, v, s);
        f16 h = (f16)v;
        ecvt[code * 128 + d]      = h;
        ecvt[code * 128 + 64 + d] = (f16)(v - (float)h);
        embt[code * 64 + d] = (v + mean) * sd;         // affine pre-applied
    }
    e2g[code] = s;
}

__global__ __launch_bounds__(256)
void vq_main(const float* __restrict__ x, const float* __restrict__ meanp,
             const float* __restrict__ sdp, const f16* __restrict__ ecvt,
             const float* __restrict__ e2g, const float* __restrict__ embt,
             float* __restrict__ out, float* __restrict__ outIdx)
{
    __shared__ int kbb[256];

    const int tid  = threadIdx.x;
    const int lane = tid & 63;
    const int wid  = tid >> 6;       // wave owns c in [wid*64, wid*64+64)
    const int lr   = lane & 15;
    const int lk   = lane >> 4;

    const int blk = blockIdx.x;      // 512 = 32 b x 16 g
    const int g   = blk & 15;
    const int b   = blk >> 4;
    const int c0  = wid * 64;

    const float sd   = sdp[0];
    const bool  sdz  = (sd == 0.0f);
    const float safe = sdz ? 1.0f : sd;
    const float mean = meanp[0];

    const size_t xslab = (size_t)b * 262144 + (size_t)g * 16384;

    // ---- A fragments for 64 rows, straight from global (no LDS) ----
    // set s: row = c0 + s*16 + lr ; MFMA k-element = lk*8 + j within each 32-block
    f16x8 ah[4][2], al[4][2];        // [set][ks: d 0-31 / 32-63]
    #pragma unroll
    for (int s = 0; s < 4; ++s) {
        const float* rp = x + xslab + c0 + s * 16 + lr;
        #pragma unroll
        for (int ks = 0; ks < 2; ++ks)
            #pragma unroll
            for (int j = 0; j < 8; ++j) {
                float v  = rp[(ks * 32 + lk * 8 + j) * 256];  // 4 full 64B lines/instr
                float sv = (sdz ? 0.0f : v / safe) - mean;
                f16 h = (f16)sv;
                ah[s][ks][j] = h;
                al[s][ks][j] = (f16)(sv - (float)h);
            }
    }

    float bestv[16];
    int   besti[16];
    #pragma unroll
    for (int s = 0; s < 16; ++s) { bestv[s] = FLTMAX; besti[s] = 0; }

    // ---- main loop: 32 code-frags, manual 2-deep B double-buffer ----
    const f16* bbase = ecvt + lr * 128 + lk * 8;   // code = cf*16 + lr
    f16x8 ba0, ba1, ba2, ba3, bb0, bb1, bb2, bb3;
    float ea, eb;
    {
        const f16* p = bbase;                       // cf = 0
        ba0 = *reinterpret_cast<const f16x8*>(p);
        ba1 = *reinterpret_cast<const f16x8*>(p + 32);
        ba2 = *reinterpret_cast<const f16x8*>(p + 64);
        ba3 = *reinterpret_cast<const f16x8*>(p + 96);
        ea  = e2g[lr];
    }

    #pragma unroll 4
    for (int cf = 0; cf < 32; cf += 2) {
        {   // prefetch cf+1
            const f16* p = bbase + (cf + 1) * 2048;
            bb0 = *reinterpret_cast<const f16x8*>(p);
            bb1 = *reinterpret_cast<const f16x8*>(p + 32);
            bb2 = *reinterpret_cast<const f16x8*>(p + 64);
            bb3 = *reinterpret_cast<const f16x8*>(p + 96);
            eb  = e2g[(cf + 1) * 16 + lr];
        }
        {   // compute cf (buffer a)
            const int code = cf * 16 + lr;
            #pragma unroll
            for (int s = 0; s < 4; ++s) {
                f32x4 acc = (f32x4){0.f, 0.f, 0.f, 0.f};
                acc = __builtin_amdgcn_mfma_f32_16x16x32_f16(ah[s][0], ba0, acc, 0, 0, 0);
                acc = __builtin_amdgcn_mfma_f32_16x16x32_f16(ah[s][1], ba1, acc, 0, 0, 0);
                acc = __builtin_amdgcn_mfma_f32_16x16x32_f16(ah[s][0], ba2, acc, 0, 0, 0);
                acc = __builtin_amdgcn_mfma_f32_16x16x32_f16(ah[s][1], ba3, acc, 0, 0, 0);
                acc = __builtin_amdgcn_mfma_f32_16x16x32_f16(al[s][0], ba0, acc, 0, 0, 0);
                acc = __builtin_amdgcn_mfma_f32_16x16x32_f16(al[s][1], ba1, acc, 0, 0, 0);
                #pragma unroll
                for (int r = 0; r < 4; ++r) {
                    float vd = fmaf(-2.0f, acc[r], ea);
                    const int si = s * 4 + r;
                    if (vd < bestv[si]) { bestv[si] = vd; besti[si] = code; }
                }
            }
        }
        if (cf + 2 < 32) {   // prefetch cf+2
            const f16* p = bbase + (cf + 2) * 2048;
            ba0 = *reinterpret_cast<const f16x8*>(p);
            ba1 = *reinterpret_cast<const f16x8*>(p + 32);
            ba2 = *reinterpret_cast<const f16x8*>(p + 64);
            ba3 = *reinterpret_cast<const f16x8*>(p + 96);
            ea  = e2g[(cf + 2) * 16 + lr];
        }
        {   // compute cf+1 (buffer b)
            const int code = (cf + 1) * 16 + lr;
            #pragma unroll
            for (int s = 0; s < 4; ++s) {
                f32x4 acc = (f32x4){0.f, 0.f, 0.f, 0.f};
                acc = __builtin_amdgcn_mfma_f32_16x16x32_f16(ah[s][0], bb0, acc, 0, 0, 0);
                acc = __builtin_amdgcn_mfma_f32_16x16x32_f16(ah[s][1], bb1, acc, 0, 0, 0);
                acc = __builtin_amdgcn_mfma_f32_16x16x32_f16(ah[s][0], bb2, acc, 0, 0, 0);
                acc = __builtin_amdgcn_mfma_f32_16x16x32_f16(ah[s][1], bb3, acc, 0, 0, 0);
                acc = __builtin_amdgcn_mfma_f32_16x16x32_f16(al[s][0], bb0, acc, 0, 0, 0);
                acc = __builtin_amdgcn_mfma_f32_16x16x32_f16(al[s][1], bb1, acc, 0, 0, 0);
                #pragma unroll
                for (int r = 0; r < 4; ++r) {
                    float vd = fmaf(-2.0f, acc[r], eb);
                    const int si = s * 4 + r;
                    if (vd < bestv[si]) { bestv[si] = vd; besti[si] = code; }
                }
            }
        }
    }

    // ---- reduce across the 16 code-columns (lanes differing in bits 0-3) ----
    #pragma unroll
    for (int s = 0; s < 16; ++s) {
        float v = bestv[s]; int i = besti[s];
        #pragma unroll
        for (int m = 1; m < 16; m <<= 1) {
            float v2 = __shfl_xor(v, m, 64);
            int   i2 = __shfl_xor(i, m, 64);
            if (v2 < v || (v2 == v && i2 < i)) { v = v2; i = i2; }
        }
        bestv[s] = v; besti[s] = i;
    }
    if (lr == 0) {
        #pragma unroll
        for (int s = 0; s < 4; ++s)
            #pragma unroll
            for (int r = 0; r < 4; ++r)
                kbb[c0 + s * 16 + lk * 4 + r] = besti[s * 4 + r];  // C/D row map
    }
    __syncthreads();

    // ---- epilogue: thread owns row c=tid; stream embT_s row, coalesced stores ----
    const int k = kbb[tid];
    const float* qrow = embt + k * 64;        // 256B, 256B-aligned, L2/L1-resident
    float* op = out + xslab + tid;
    #pragma unroll
    for (int dc = 0; dc < 4; ++dc) {
        f32x4 q0 = *reinterpret_cast<const f32x4*>(qrow + dc * 16);
        f32x4 q1 = *reinterpret_cast<const f32x4*>(qrow + dc * 16 + 4);
        f32x4 q2 = *reinterpret_cast<const f32x4*>(qrow + dc * 16 + 8);
        f32x4 q3 = *reinterpret_cast<const f32x4*>(qrow + dc * 16 + 12);
        #pragma unroll
        for (int j = 0; j < 4; ++j) op[(dc * 16 + j)      * 256] = q0[j];
        #pragma unroll
        for (int j = 0; j < 4; ++j) op[(dc * 16 + 4 + j)  * 256] = q1[j];
        #pragma unroll
        for (int j = 0; j < 4; ++j) op[(dc * 16 + 8 + j)  * 256] = q2[j];
        #pragma unroll
        for (int j = 0; j < 4; ++j) op[(dc * 16 + 12 + j) * 256] = q3[j];
    }
    outIdx[(size_t)(b * 256 + tid) * 16 + g] = (float)k;
}

// ---------------- fallback (ws too small): R5-style self-contained -------------
__device__ __forceinline__ int swz(int row, int koff) {
    return row * 128 + (koff ^ ((row & 7) << 3));
}

__global__ __launch_bounds__(512, 2)
void vq_fallback(const float* __restrict__ x, const float* __restrict__ meanp,
                 const float* __restrict__ sdp, const float* __restrict__ emb,
                 float* __restrict__ out, float* __restrict__ outIdx)
{
    __shared__ __align__(16) f16 xa[128 * 128];
    __shared__ __align__(16) f16 es[128 * 128];
    __shared__ float e2s[512];
    __shared__ float red_v[4][128];
    __shared__ int   red_i[4][128];
    __shared__ int   kb[128];

    const int tid  = threadIdx.x;
    const int lane = tid & 63;
    const int wid  = tid >> 6;
    const int wr   = wid >> 2;
    const int wc   = wid & 3;
    const int lr   = lane & 15;
    const int lk   = lane >> 4;

    const int blk   = blockIdx.x;
    const int chalf = blk & 1;
    const int g     = (blk >> 1) & 15;
    const int b     = blk >> 5;

    const float mean = meanp[0];
    const float sd   = sdp[0];
    const bool  sdz  = (sd == 0.0f);
    const float safe = sdz ? 1.0f : sd;

    const int xbase = b * 262144 + g * 16384 + chalf * 128;

    {
        const int c_ = tid & 127;
        const int dq = tid >> 7;
        const float* src = x + xbase + c_;
        #pragma unroll
        for (int jv = 0; jv < 2; ++jv) {
            f16x8 hi, lo;
            #pragma unroll
            for (int e = 0; e < 8; ++e) {
                int d = dq * 16 + jv * 8 + e;
                float v = src[d * 256];
                float s = (sdz ? 0.0f : v / safe) - mean;
                f16 h = (f16)s;
                hi[e] = h;
                lo[e] = (f16)(s - (float)h);
            }
            *reinterpret_cast<f16x8*>(&xa[swz(c_, dq * 16 + jv * 8)])      = hi;
            *reinterpret_cast<f16x8*>(&xa[swz(c_, 64 + dq * 16 + jv * 8)]) = lo;
        }
    }
    {
        float s = 0.0f;
        for (int d = 0; d < 64; ++d) {
            float v = emb[d * 512 + tid];
            s = fmaf(v, v, s);
        }
        e2s[tid] = s;
    }

    float bestv[16];
    int   besti[16];
    #pragma unroll
    for (int s = 0; s < 16; ++s) { bestv[s] = FLTMAX; besti[s] = 0; }

    for (int ch = 0; ch < 4; ++ch) {
        __syncthreads();
        {
            const int cl = tid & 127;
            const int dq = tid >> 7;
            const float* srcE = emb + ch * 128 + cl;
            #pragma unroll
            for (int jv = 0; jv < 2; ++jv) {
                f16x8 hi, lo;
                #pragma unroll
                for (int e = 0; e < 8; ++e) {
                    int d = dq * 16 + jv * 8 + e;
                    float v = srcE[d * 512];
                    f16 h = (f16)v;
                    hi[e] = h;
                    lo[e] = (f16)(v - (float)h);
                }
                *reinterpret_cast<f16x8*>(&es[swz(cl, dq * 16 + jv * 8)])      = hi;
                *reinterpret_cast<f16x8*>(&es[swz(cl, 64 + dq * 16 + jv * 8)]) = lo;
            }
        }
        __syncthreads();

        f32x4 acc[4][2];
        #pragma unroll
        for (int fi = 0; fi < 4; ++fi)
            #pragma unroll
            for (int fj = 0; fj < 2; ++fj)
                acc[fi][fj] = (f32x4){0.f, 0.f, 0.f, 0.f};

        #pragma unroll
        for (int t = 0; t < 3; ++t) {
            const int ah2 = (t == 2) ? 1 : 0;
            const int eh2 = (t == 1) ? 1 : 0;
            #pragma unroll
            for (int dh2 = 0; dh2 < 2; ++dh2) {
                const int kB = eh2 * 64 + dh2 * 32 + lk * 8;
                const int kA = ah2 * 64 + dh2 * 32 + lk * 8;
                f16x8 bf[2], af[4];
                #pragma unroll
                for (int fj = 0; fj < 2; ++fj)
                    bf[fj] = *reinterpret_cast<const f16x8*>(
                        &es[swz(wc * 32 + fj * 16 + lr, kB)]);
                #pragma unroll
                for (int fi = 0; fi < 4; ++fi)
                    af[fi] = *reinterpret_cast<const f16x8*>(
                        &xa[swz(wr * 64 + fi * 16 + lr, kA)]);
                #pragma unroll
                for (int fi = 0; fi < 4; ++fi)
                    #pragma unroll
                    for (int fj = 0; fj < 2; ++fj)
                        acc[fi][fj] = __builtin_amdgcn_mfma_f32_16x16x32_f16(
                            af[fi], bf[fj], acc[fi][fj], 0, 0, 0);
            }
        }

        #pragma unroll
        for (int fj = 0; fj < 2; ++fj) {
            const int codeg = ch * 128 + wc * 32 + fj * 16 + lr;
            const float e2v = e2s[codeg];
            #pragma unroll
            for (int fi = 0; fi < 4; ++fi)
                #pragma unroll
                for (int r = 0; r < 4; ++r) {
                    float vd = fmaf(-2.0f, acc[fi][fj][r], e2v);
                    const int s = fi * 4 + r;
                    if (vd < bestv[s]) { bestv[s] = vd; besti[s] = codeg; }
                }
        }
    }

    #pragma unroll
    for (int s = 0; s < 16; ++s) {
        float v = bestv[s]; int i = besti[s];
        #pragma unroll
        for (int m = 1; m < 16; m <<= 1) {
            float v2 = __shfl_xor(v, m, 64);
            int   i2 = __shfl_xor(i, m, 64);
            if (v2 < v || (v2 == v && i2 < i)) { v = v2; i = i2; }
        }
        bestv[s] = v; besti[s] = i;
    }
    if (lr == 0) {
        #pragma unroll
        for (int fi = 0; fi < 4; ++fi)
            #pragma unroll
            for (int r = 0; r < 4; ++r) {
                int row = wr * 64 + fi * 16 + lk * 4 + r;
                red_v[wc][row] = bestv[fi * 4 + r];
                red_i[wc][row] = besti[fi * 4 + r];
            }
    }
    __syncthreads();
    if (tid < 128) {
        float bv = red_v[0][tid]; int bi = red_i[0][tid];
        #pragma unroll
        for (int w = 1; w < 4; ++w) {
            float v = red_v[w][tid]; int i = red_i[w][tid];
            if (v < bv || (v == bv && i < bi)) { bv = v; bi = i; }
        }
        kb[tid] = bi;
    }
    __syncthreads();

    float* out_ = out + xbase;
    #pragma unroll 4
    for (int i = 0; i < 16; ++i) {
        int lin = i * 512 + tid;
        int c_  = lin & 127;
        int d   = lin >> 7;
        float q = emb[d * 512 + kb[c_]];
        out_[d * 256 + c_] = (q + mean) * sd;
    }
    if (tid < 128) {
        int n = (b * 256 + chalf * 128 + tid) * 16 + g;
        outIdx[n] = (float)kb[tid];
    }
}

extern "C" void kernel_launch(void* const* d_in, const int* in_sizes, int n_in,
                              void* d_out, int out_size, void* d_ws, size_t ws_size,
                              hipStream_t stream) {
    const float* x    = (const float*)d_in[0];
    const float* mean = (const float*)d_in[1];
    const float* sd   = (const float*)d_in[2];
    const float* emb  = (const float*)d_in[3];
    float* out    = (float*)d_out;
    float* outIdx = out + NELEM0;

    if (ws_size >= (size_t)WS_NEED) {
        f16*   ecvt = (f16*)d_ws;
        float* e2g  = (float*)((char*)d_ws + 131072);
        float* embt = (float*)((char*)d_ws + 133120);
        prep_kernel<<<dim3(2), dim3(256), 0, stream>>>(emb, mean, sd, ecvt, e2g, embt);
        vq_main<<<dim3(512), dim3(256), 0, stream>>>(x, mean, sd, ecvt, e2g, embt, out, outIdx);
    } else {
        vq_fallback<<<dim3(1024), dim3(512), 0, stream>>>(x, mean, sd, emb, out, outIdx);
    }
}

// Round 8
// 86.316 us; speedup vs baseline: 1.1802x; 1.1802x over previous
//
#include <hip/hip_runtime.h>

// VectorQuantiser R8: one wave per block, zero barriers, max TLP.
//  prep: ecvt f16-split codebook [512][128], e2[512], embT_s[512][64]=(emb+mean)*sd.
//  main: 4096 blocks x 64 thr (1 wave, 32 rows). A frags (32 rows) built straight
//  from global into regs; B double-buffered from L2-resident ecvt (12 MFMA : 4 loads);
//  in-wave shfl argmin; streaming epilogue from embT_s. ~100 VGPR -> 4 waves/SIMD.
// dist = e2[k] - 2*(xh·eh + xh·el + xl·eh)  (x2 dropped: argmin-invariant;
// scheme validated R3-R7: index output exact).

typedef _Float16 f16;
typedef _Float16 f16x8 __attribute__((ext_vector_type(8)));
typedef float    f32x4 __attribute__((ext_vector_type(4)));

#define NELEM0 8388608
#define FLTMAX 3.402823466e38f
// ws: [0,131072) ecvt f16[512][128]; [131072,133120) e2 f32[512];
//     [133120,264192) embT_s f32[512][64]
#define WS_NEED 264192

__global__ void prep_kernel(const float* __restrict__ emb, const float* __restrict__ meanp,
                            const float* __restrict__ sdp, f16* __restrict__ ecvt,
                            float* __restrict__ e2g, float* __restrict__ embt) {
    const int code = blockIdx.x * 256 + threadIdx.x;   // 512 total
    const float mean = meanp[0];
    const float sd   = sdp[0];
    float s = 0.0f;
    #pragma unroll 8
    for (int d = 0; d < 64; ++d) {
        float v = emb[d * 512 + code];                 // coalesced across codes
        s = fmaf(v, v, s);
        f16 h = (f16)v;
        ecvt[code * 128 + d]      = h;
        ecvt[code * 128 + 64 + d] = (f16)(v - (float)h);
        embt[code * 64 + d] = (v + mean) * sd;         // affine pre-applied
    }
    e2g[code] = s;
}

__global__ __launch_bounds__(64, 4)
void vq_wave(const float* __restrict__ x, const float* __restrict__ meanp,
             const float* __restrict__ sdp, const f16* __restrict__ ecvt,
             const float* __restrict__ e2g, const float* __restrict__ embt,
             float* __restrict__ out, float* __restrict__ outIdx)
{
    __shared__ int kbs[32];

    const int lane = threadIdx.x;    // 0..63
    const int lr   = lane & 15;
    const int lk   = lane >> 4;

    const int blk = blockIdx.x;      // 4096 = 32 b x 16 g x 8 cq
    const int cq  = blk & 7;
    const int g   = (blk >> 3) & 15;
    const int b   = blk >> 7;
    const int c0  = cq * 32;

    const float sd   = sdp[0];
    const bool  sdz  = (sd == 0.0f);
    const float sinv = sdz ? 0.0f : (1.0f / sd);   // divide_no_nan: 0 when sd==0
    const float mean = meanp[0];

    const size_t xslab = (size_t)b * 262144 + (size_t)g * 16384;

    // ---- A fragments for 32 rows, straight from global (no LDS) ----
    // set s: row = c0 + s*16 + lr ; k-element = lk*8 + j within each 32-d block
    f16x8 ah[2][2], al[2][2];        // [set][ks: d 0-31 / 32-63]
    #pragma unroll
    for (int s = 0; s < 2; ++s) {
        const float* rp = x + xslab + c0 + s * 16 + lr;
        #pragma unroll
        for (int ks = 0; ks < 2; ++ks)
            #pragma unroll
            for (int j = 0; j < 8; ++j) {
                float v  = rp[(ks * 32 + lk * 8 + j) * 256];  // coalesced across lr
                float sv = fmaf(v, sinv, -mean);
                f16 h = (f16)sv;
                ah[s][ks][j] = h;
                al[s][ks][j] = (f16)(sv - (float)h);
            }
    }

    float bestv[8];
    int   besti[8];
    #pragma unroll
    for (int s = 0; s < 8; ++s) { bestv[s] = FLTMAX; besti[s] = 0; }

    // ---- main loop: 32 code-frags, 2-deep ping-pong B prefetch from L2 ----
    const f16* bbase = ecvt + lr * 128 + lk * 8;   // code = cf*16 + lr
    f16x8 ba0, ba1, ba2, ba3, bb0, bb1, bb2, bb3;
    float ea, eb;
    {
        const f16* p = bbase;                       // cf = 0
        ba0 = *reinterpret_cast<const f16x8*>(p);
        ba1 = *reinterpret_cast<const f16x8*>(p + 32);
        ba2 = *reinterpret_cast<const f16x8*>(p + 64);
        ba3 = *reinterpret_cast<const f16x8*>(p + 96);
        ea  = e2g[lr];
    }

    for (int cf = 0; cf < 32; cf += 2) {
        {   // prefetch cf+1
            const f16* p = bbase + (cf + 1) * 2048;
            bb0 = *reinterpret_cast<const f16x8*>(p);
            bb1 = *reinterpret_cast<const f16x8*>(p + 32);
            bb2 = *reinterpret_cast<const f16x8*>(p + 64);
            bb3 = *reinterpret_cast<const f16x8*>(p + 96);
            eb  = e2g[(cf + 1) * 16 + lr];
        }
        {   // compute cf (buffer a)
            const int code = cf * 16 + lr;
            #pragma unroll
            for (int s = 0; s < 2; ++s) {
                f32x4 acc = (f32x4){0.f, 0.f, 0.f, 0.f};
                acc = __builtin_amdgcn_mfma_f32_16x16x32_f16(ah[s][0], ba0, acc, 0, 0, 0);
                acc = __builtin_amdgcn_mfma_f32_16x16x32_f16(ah[s][1], ba1, acc, 0, 0, 0);
                acc = __builtin_amdgcn_mfma_f32_16x16x32_f16(ah[s][0], ba2, acc, 0, 0, 0);
                acc = __builtin_amdgcn_mfma_f32_16x16x32_f16(ah[s][1], ba3, acc, 0, 0, 0);
                acc = __builtin_amdgcn_mfma_f32_16x16x32_f16(al[s][0], ba0, acc, 0, 0, 0);
                acc = __builtin_amdgcn_mfma_f32_16x16x32_f16(al[s][1], ba1, acc, 0, 0, 0);
                #pragma unroll
                for (int r = 0; r < 4; ++r) {
                    float vd = fmaf(-2.0f, acc[r], ea);
                    const int si = s * 4 + r;
                    if (vd < bestv[si]) { bestv[si] = vd; besti[si] = code; }
                }
            }
        }
        if (cf + 2 < 32) {   // prefetch cf+2
            const f16* p = bbase + (cf + 2) * 2048;
            ba0 = *reinterpret_cast<const f16x8*>(p);
            ba1 = *reinterpret_cast<const f16x8*>(p + 32);
            ba2 = *reinterpret_cast<const f16x8*>(p + 64);
            ba3 = *reinterpret_cast<const f16x8*>(p + 96);
            ea  = e2g[(cf + 2) * 16 + lr];
        }
        {   // compute cf+1 (buffer b)
            const int code = (cf + 1) * 16 + lr;
            #pragma unroll
            for (int s = 0; s < 2; ++s) {
                f32x4 acc = (f32x4){0.f, 0.f, 0.f, 0.f};
                acc = __builtin_amdgcn_mfma_f32_16x16x32_f16(ah[s][0], bb0, acc, 0, 0, 0);
                acc = __builtin_amdgcn_mfma_f32_16x16x32_f16(ah[s][1], bb1, acc, 0, 0, 0);
                acc = __builtin_amdgcn_mfma_f32_16x16x32_f16(ah[s][0], bb2, acc, 0, 0, 0);
                acc = __builtin_amdgcn_mfma_f32_16x16x32_f16(ah[s][1], bb3, acc, 0, 0, 0);
                acc = __builtin_amdgcn_mfma_f32_16x16x32_f16(al[s][0], bb0, acc, 0, 0, 0);
                acc = __builtin_amdgcn_mfma_f32_16x16x32_f16(al[s][1], bb1, acc, 0, 0, 0);
                #pragma unroll
                for (int r = 0; r < 4; ++r) {
                    float vd = fmaf(-2.0f, acc[r], eb);
                    const int si = s * 4 + r;
                    if (vd < bestv[si]) { bestv[si] = vd; besti[si] = code; }
                }
            }
        }
    }

    // ---- in-wave argmin reduce over the 16 code-columns (lane bits 0-3) ----
    #pragma unroll
    for (int si = 0; si < 8; ++si) {
        float v = bestv[si]; int i = besti[si];
        #pragma unroll
        for (int m = 1; m < 16; m <<= 1) {
            float v2 = __shfl_xor(v, m, 64);
            int   i2 = __shfl_xor(i, m, 64);
            if (v2 < v || (v2 == v && i2 < i)) { v = v2; i = i2; }
        }
        bestv[si] = v; besti[si] = i;
    }
    if (lr == 0) {
        #pragma unroll
        for (int s = 0; s < 2; ++s)
            #pragma unroll
            for (int r = 0; r < 4; ++r)
                kbs[s * 16 + lk * 4 + r] = besti[s * 4 + r];   // C/D row map
    }
    __syncthreads();   // single wave: compiles to a cheap fence

    // ---- epilogue: lane pair per row; stream embT_s row, write d-major ----
    const int row = lane >> 1;             // 0..31
    const int dh  = (lane & 1) * 32;       // d-half
    const int k   = kbs[row];
    const float* qrow = embt + k * 64 + dh;     // 128B, L2/L1-resident
    float* op = out + xslab + (size_t)dh * 256 + c0 + row;
    #pragma unroll
    for (int q4 = 0; q4 < 8; ++q4) {
        f32x4 qq = *reinterpret_cast<const f32x4*>(qrow + q4 * 4);
        #pragma unroll
        for (int j = 0; j < 4; ++j)
            op[(q4 * 4 + j) * 256] = qq[j];
    }
    if (lane < 32) {
        int n = (b * 256 + c0 + lane) * 16 + g;
        outIdx[n] = (float)kbs[lane];
    }
}

// ---------------- fallback (ws too small): R5-style self-contained -------------
__device__ __forceinline__ int swz(int row, int koff) {
    return row * 128 + (koff ^ ((row & 7) << 3));
}

__global__ __launch_bounds__(512, 2)
void vq_fallback(const float* __restrict__ x, const float* __restrict__ meanp,
                 const float* __restrict__ sdp, const float* __restrict__ emb,
                 float* __restrict__ out, float* __restrict__ outIdx)
{
    __shared__ __align__(16) f16 xa[128 * 128];
    __shared__ __align__(16) f16 es[128 * 128];
    __shared__ float e2s[512];
    __shared__ float red_v[4][128];
    __shared__ int   red_i[4][128];
    __shared__ int   kb[128];

    const int tid  = threadIdx.x;
    const int lane = tid & 63;
    const int wid  = tid >> 6;
    const int wr   = wid >> 2;
    const int wc   = wid & 3;
    const int lr   = lane & 15;
    const int lk   = lane >> 4;

    const int blk   = blockIdx.x;
    const int chalf = blk & 1;
    const int g     = (blk >> 1) & 15;
    const int b     = blk >> 5;

    const float mean = meanp[0];
    const float sd   = sdp[0];
    const bool  sdz  = (sd == 0.0f);
    const float safe = sdz ? 1.0f : sd;

    const int xbase = b * 262144 + g * 16384 + chalf * 128;

    {
        const int c_ = tid & 127;
        const int dq = tid >> 7;
        const float* src = x + xbase + c_;
        #pragma unroll
        for (int jv = 0; jv < 2; ++jv) {
            f16x8 hi, lo;
            #pragma unroll
            for (int e = 0; e < 8; ++e) {
                int d = dq * 16 + jv * 8 + e;
                float v = src[d * 256];
                float s = (sdz ? 0.0f : v / safe) - mean;
                f16 h = (f16)s;
                hi[e] = h;
                lo[e] = (f16)(s - (float)h);
            }
            *reinterpret_cast<f16x8*>(&xa[swz(c_, dq * 16 + jv * 8)])      = hi;
            *reinterpret_cast<f16x8*>(&xa[swz(c_, 64 + dq * 16 + jv * 8)]) = lo;
        }
    }
    {
        float s = 0.0f;
        for (int d = 0; d < 64; ++d) {
            float v = emb[d * 512 + tid];
            s = fmaf(v, v, s);
        }
        e2s[tid] = s;
    }

    float bestv[16];
    int   besti[16];
    #pragma unroll
    for (int s = 0; s < 16; ++s) { bestv[s] = FLTMAX; besti[s] = 0; }

    for (int ch = 0; ch < 4; ++ch) {
        __syncthreads();
        {
            const int cl = tid & 127;
            const int dq = tid >> 7;
            const float* srcE = emb + ch * 128 + cl;
            #pragma unroll
            for (int jv = 0; jv < 2; ++jv) {
                f16x8 hi, lo;
                #pragma unroll
                for (int e = 0; e < 8; ++e) {
                    int d = dq * 16 + jv * 8 + e;
                    float v = srcE[d * 512];
                    f16 h = (f16)v;
                    hi[e] = h;
                    lo[e] = (f16)(v - (float)h);
                }
                *reinterpret_cast<f16x8*>(&es[swz(cl, dq * 16 + jv * 8)])      = hi;
                *reinterpret_cast<f16x8*>(&es[swz(cl, 64 + dq * 16 + jv * 8)]) = lo;
            }
        }
        __syncthreads();

        f32x4 acc[4][2];
        #pragma unroll
        for (int fi = 0; fi < 4; ++fi)
            #pragma unroll
            for (int fj = 0; fj < 2; ++fj)
                acc[fi][fj] = (f32x4){0.f, 0.f, 0.f, 0.f};

        #pragma unroll
        for (int t = 0; t < 3; ++t) {
            const int ah2 = (t == 2) ? 1 : 0;
            const int eh2 = (t == 1) ? 1 : 0;
            #pragma unroll
            for (int dh2 = 0; dh2 < 2; ++dh2) {
                const int kB = eh2 * 64 + dh2 * 32 + lk * 8;
                const int kA = ah2 * 64 + dh2 * 32 + lk * 8;
                f16x8 bf[2], af[4];
                #pragma unroll
                for (int fj = 0; fj < 2; ++fj)
                    bf[fj] = *reinterpret_cast<const f16x8*>(
                        &es[swz(wc * 32 + fj * 16 + lr, kB)]);
                #pragma unroll
                for (int fi = 0; fi < 4; ++fi)
                    af[fi] = *reinterpret_cast<const f16x8*>(
                        &xa[swz(wr * 64 + fi * 16 + lr, kA)]);
                #pragma unroll
                for (int fi = 0; fi < 4; ++fi)
                    #pragma unroll
                    for (int fj = 0; fj < 2; ++fj)
                        acc[fi][fj] = __builtin_amdgcn_mfma_f32_16x16x32_f16(
                            af[fi], bf[fj], acc[fi][fj], 0, 0, 0);
            }
        }

        #pragma unroll
        for (int fj = 0; fj < 2; ++fj) {
            const int codeg = ch * 128 + wc * 32 + fj * 16 + lr;
            const float e2v = e2s[codeg];
            #pragma unroll
            for (int fi = 0; fi < 4; ++fi)
                #pragma unroll
                for (int r = 0; r < 4; ++r) {
                    float vd = fmaf(-2.0f, acc[fi][fj][r], e2v);
                    const int s = fi * 4 + r;
                    if (vd < bestv[s]) { bestv[s] = vd; besti[s] = codeg; }
                }
        }
    }

    #pragma unroll
    for (int s = 0; s < 16; ++s) {
        float v = bestv[s]; int i = besti[s];
        #pragma unroll
        for (int m = 1; m < 16; m <<= 1) {
            float v2 = __shfl_xor(v, m, 64);
            int   i2 = __shfl_xor(i, m, 64);
            if (v2 < v || (v2 == v && i2 < i)) { v = v2; i = i2; }
        }
        bestv[s] = v; besti[s] = i;
    }
    if (lr == 0) {
        #pragma unroll
        for (int fi = 0; fi < 4; ++fi)
            #pragma unroll
            for (int r = 0; r < 4; ++r) {
                int row = wr * 64 + fi * 16 + lk * 4 + r;
                red_v[wc][row] = bestv[fi * 4 + r];
                red_i[wc][row] = besti[fi * 4 + r];
            }
    }
    __syncthreads();
    if (tid < 128) {
        float bv = red_v[0][tid]; int bi = red_i[0][tid];
        #pragma unroll
        for (int w = 1; w < 4; ++w) {
            float v = red_v[w][tid]; int i = red_i[w][tid];
            if (v < bv || (v == bv && i < bi)) { bv = v; bi = i; }
        }
        kb[tid] = bi;
    }
    __syncthreads();

    float* out_ = out + xbase;
    #pragma unroll 4
    for (int i = 0; i < 16; ++i) {
        int lin = i * 512 + tid;
        int c_  = lin & 127;
        int d   = lin >> 7;
        float q = emb[d * 512 + kb[c_]];
        out_[d * 256 + c_] = (q + mean) * sd;
    }
    if (tid < 128) {
        int n = (b * 256 + chalf * 128 + tid) * 16 + g;
        outIdx[n] = (float)kb[tid];
    }
}

extern "C" void kernel_launch(void* const* d_in, const int* in_sizes, int n_in,
                              void* d_out, int out_size, void* d_ws, size_t ws_size,
                              hipStream_t stream) {
    const float* x    = (const float*)d_in[0];
    const float* mean = (const float*)d_in[1];
    const float* sd   = (const float*)d_in[2];
    const float* emb  = (const float*)d_in[3];
    float* out    = (float*)d_out;
    float* outIdx = out + NELEM0;

    if (ws_size >= (size_t)WS_NEED) {
        f16*   ecvt = (f16*)d_ws;
        float* e2g  = (float*)((char*)d_ws + 131072);
        float* embt = (float*)((char*)d_ws + 133120);
        prep_kernel<<<dim3(2), dim3(256), 0, stream>>>(emb, mean, sd, ecvt, e2g, embt);
        vq_wave<<<dim3(4096), dim3(64), 0, stream>>>(x, mean, sd, ecvt, e2g, embt, out, outIdx);
    } else {
        vq_fallback<<<dim3(1024), dim3(512), 0, stream>>>(x, mean, sd, emb, out, outIdx);
    }
}

// Round 9
// 69.461 us; speedup vs baseline: 1.4666x; 1.2427x over previous
//
#include <hip/hip_runtime.h>

// VectorQuantiser R9: contiguous-only global traffic; MFMA fed from LDS.
// Lesson R6-R8: lane-scattered global B-loads (16 lines/instr) serialize the
// CU memory pipe (~16 transactions/instr) -> all pipes idle. Fix: stage the
// f16-split codebook chunk-wise into LDS via CONTIGUOUS loads from a
// PRE-SWIZZLED ecvt (prep applies inverse XOR), double-buffered (T14 split).
// Block: 512 thr / 8 waves; 256 rows x 512 codes; 4 chunks x 128 codes;
// wave tile 64x64 (4x4 16x16x32_f16 frags); dist = e2[k]-2*(xh.eh+xh.el+xl.eh).
// LDS: xa 64K + es 2x32K + e2s 2K = 130 KB -> 1 block/CU (8 waves).

typedef _Float16 f16;
typedef _Float16 f16x8 __attribute__((ext_vector_type(8)));
typedef float    f32x4 __attribute__((ext_vector_type(4)));

#define NELEM0 8388608
#define FLTMAX 3.402823466e38f
// ws: [0,131072) ecvt_sw f16[512][128] pre-swizzled; [131072,139264) e2p f32[4][512];
//     [139264,270336) embt f32[512][64]
#define WS_NEED 270336

// LDS read swizzle: f16 index = row*128 + (koff ^ ((row&7)<<3))
__device__ __forceinline__ int swz(int row, int koff) {
    return row * 128 + (koff ^ ((row & 7) << 3));
}

// prep: 8 blocks x 256 thr. block = (code-half)<<2 | d-chunk.
__global__ void prep_kernel(const float* __restrict__ emb, const float* __restrict__ meanp,
                            const float* __restrict__ sdp, f16* __restrict__ ecvt,
                            float* __restrict__ e2p, float* __restrict__ embt) {
    const int code = (blockIdx.x >> 2) * 256 + threadIdx.x;
    const int dc   = blockIdx.x & 3;                 // 16 d's per block
    const float mean = meanp[0];
    const float sd   = sdp[0];
    float s = 0.0f;
    #pragma unroll
    for (int j = 0; j < 16; ++j) {
        const int d = dc * 16 + j;
        float v = emb[d * 512 + code];               // coalesced across codes
        s = fmaf(v, v, s);
        f16 h = (f16)v;
        f16 l = (f16)(v - (float)h);
        const int gg = (d >> 3) ^ (code & 7);        // pre-apply inverse swizzle
        const int e  = d & 7;
        ecvt[code * 128 + gg * 8 + e]      = h;      // eh groups 0-7
        ecvt[code * 128 + 64 + gg * 8 + e] = l;      // el groups 8-15
        embt[code * 64 + d] = (v + mean) * sd;       // affine pre-applied
    }
    e2p[dc * 512 + code] = s;
}

__global__ __launch_bounds__(512)
void vq_main(const float* __restrict__ x, const float* __restrict__ meanp,
             const float* __restrict__ sdp, const f16* __restrict__ ecvt,
             const float* __restrict__ e2p, const float* __restrict__ embt,
             float* __restrict__ out, float* __restrict__ outIdx)
{
    __shared__ __align__(16) f16 xa[256 * 128];      // 64 KB, swizzled
    __shared__ __align__(16) f16 es[2][128 * 128];   // 2 x 32 KB, linear copy of pre-swizzled
    __shared__ float e2s[512];

    const int tid  = threadIdx.x;
    const int lane = tid & 63;
    const int wid  = tid >> 6;       // 0..7
    const int lr   = lane & 15;
    const int lk   = lane >> 4;
    const int wr   = wid >> 1;       // row quarter (64 rows)
    const int wc   = wid & 1;        // code half within 128-chunk (64 codes)

    const int g = blockIdx.x & 15;   // 512 blocks = 32 b x 16 g
    const int b = blockIdx.x >> 4;
    const size_t xslab = (size_t)b * 262144 + (size_t)g * 16384;

    const float sd   = sdp[0];
    const bool  sdz  = (sd == 0.0f);
    const float sinv = sdz ? 0.0f : (1.0f / sd);
    const float mean = meanp[0];

    // ---- stage xa (256 rows), coalesced loads, swizzled writes ----
    {
        const int c_ = tid & 255;
        const int dh = tid >> 8;                     // d half (32 each)
        const float* src = x + xslab + c_;
        #pragma unroll
        for (int jv = 0; jv < 4; ++jv) {
            f16x8 hi, lo;
            #pragma unroll
            for (int e = 0; e < 8; ++e) {
                const int d = dh * 32 + jv * 8 + e;
                float v  = src[d * 256];             // lanes = consecutive c
                float sv = fmaf(v, sinv, -mean);
                f16 h = (f16)sv;
                hi[e] = h;
                lo[e] = (f16)(sv - (float)h);
            }
            *reinterpret_cast<f16x8*>(&xa[swz(c_, dh * 32 + jv * 8)])      = hi;
            *reinterpret_cast<f16x8*>(&xa[swz(c_, 64 + dh * 32 + jv * 8)]) = lo;
        }
    }
    e2s[tid] = e2p[tid] + e2p[512 + tid] + e2p[1024 + tid] + e2p[1536 + tid];

    // ---- prologue: stage chunk 0 (contiguous 16B per thread x4) ----
    f16x8 pre[4];
    #pragma unroll
    for (int i = 0; i < 4; ++i)
        pre[i] = *reinterpret_cast<const f16x8*>(&ecvt[i * 4096 + tid * 8]);
    #pragma unroll
    for (int i = 0; i < 4; ++i)
        *reinterpret_cast<f16x8*>(&es[0][i * 4096 + tid * 8]) = pre[i];
    __syncthreads();

    float bestv[16];
    int   besti[16];
    #pragma unroll
    for (int s = 0; s < 16; ++s) { bestv[s] = FLTMAX; besti[s] = 0; }

    const int R0 = wr * 64;
    const int C0 = wc * 64;

    #pragma unroll
    for (int ch = 0; ch < 4; ++ch) {
        const f16* eb = &es[ch & 1][0];

        // issue next-chunk global loads EARLY (contiguous, 1 txn/instr)
        if (ch < 3) {
            #pragma unroll
            for (int i = 0; i < 4; ++i)
                pre[i] = *reinterpret_cast<const f16x8*>(
                    &ecvt[(ch + 1) * 16384 + i * 4096 + tid * 8]);
        }

        f32x4 acc[4][4];
        #pragma unroll
        for (int fi = 0; fi < 4; ++fi)
            #pragma unroll
            for (int fj = 0; fj < 4; ++fj)
                acc[fi][fj] = (f32x4){0.f, 0.f, 0.f, 0.f};

        #pragma unroll
        for (int dh2 = 0; dh2 < 2; ++dh2) {
            f16x8 ah4[4], al4[4], bh4[4], bl4[4];
            #pragma unroll
            for (int fi = 0; fi < 4; ++fi) {
                ah4[fi] = *reinterpret_cast<const f16x8*>(
                    &xa[swz(R0 + fi * 16 + lr, dh2 * 32 + lk * 8)]);
                al4[fi] = *reinterpret_cast<const f16x8*>(
                    &xa[swz(R0 + fi * 16 + lr, 64 + dh2 * 32 + lk * 8)]);
            }
            #pragma unroll
            for (int fj = 0; fj < 4; ++fj) {
                bh4[fj] = *reinterpret_cast<const f16x8*>(
                    &eb[swz(C0 + fj * 16 + lr, dh2 * 32 + lk * 8)]);
                bl4[fj] = *reinterpret_cast<const f16x8*>(
                    &eb[swz(C0 + fj * 16 + lr, 64 + dh2 * 32 + lk * 8)]);
            }
            #pragma unroll
            for (int fi = 0; fi < 4; ++fi)
                #pragma unroll
                for (int fj = 0; fj < 4; ++fj) {
                    acc[fi][fj] = __builtin_amdgcn_mfma_f32_16x16x32_f16(ah4[fi], bh4[fj], acc[fi][fj], 0, 0, 0);
                    acc[fi][fj] = __builtin_amdgcn_mfma_f32_16x16x32_f16(ah4[fi], bl4[fj], acc[fi][fj], 0, 0, 0);
                    acc[fi][fj] = __builtin_amdgcn_mfma_f32_16x16x32_f16(al4[fi], bh4[fj], acc[fi][fj], 0, 0, 0);
                }
        }

        // distances + running argmin (codes ascend everywhere)
        #pragma unroll
        for (int fj = 0; fj < 4; ++fj) {
            const int codeg = ch * 128 + C0 + fj * 16 + lr;
            const float e2v = e2s[codeg];
            #pragma unroll
            for (int fi = 0; fi < 4; ++fi)
                #pragma unroll
                for (int r = 0; r < 4; ++r) {
                    float vd = fmaf(-2.0f, acc[fi][fj][r], e2v);
                    const int si = fi * 4 + r;
                    if (vd < bestv[si]) { bestv[si] = vd; besti[si] = codeg; }
                }
        }

        // write next chunk to the other buffer LATE (T14), then barrier
        if (ch < 3) {
            #pragma unroll
            for (int i = 0; i < 4; ++i)
                *reinterpret_cast<f16x8*>(&es[(ch + 1) & 1][i * 4096 + tid * 8]) = pre[i];
        }
        __syncthreads();
    }

    // ---- in-wave reduce over 16 code-columns ----
    #pragma unroll
    for (int si = 0; si < 16; ++si) {
        float v = bestv[si]; int i = besti[si];
        #pragma unroll
        for (int m = 1; m < 16; m <<= 1) {
            float v2 = __shfl_xor(v, m, 64);
            int   i2 = __shfl_xor(i, m, 64);
            if (v2 < v || (v2 == v && i2 < i)) { v = v2; i = i2; }
        }
        bestv[si] = v; besti[si] = i;
    }

    // ---- cross-wave merge (wc halves), reduce area aliases es[0] (free now) ----
    float* red_v = reinterpret_cast<float*>(&es[0][0]);           // [2][256]
    int*   red_i = reinterpret_cast<int*>((char*)&es[0][0] + 2048);
    int*   kbx   = reinterpret_cast<int*>((char*)&es[0][0] + 4096);
    if (lr == 0) {
        #pragma unroll
        for (int fi = 0; fi < 4; ++fi)
            #pragma unroll
            for (int r = 0; r < 4; ++r) {
                const int row = R0 + fi * 16 + lk * 4 + r;        // C/D layout row
                red_v[wc * 256 + row] = bestv[fi * 4 + r];
                red_i[wc * 256 + row] = besti[fi * 4 + r];
            }
    }
    __syncthreads();
    if (tid < 256) {
        float v0 = red_v[tid],       v1 = red_v[256 + tid];
        int   i0 = red_i[tid],       i1 = red_i[256 + tid];
        kbx[tid] = (v1 < v0 || (v1 == v0 && i1 < i0)) ? i1 : i0;
    }
    __syncthreads();

    // ---- epilogue: lanes = consecutive c for coalesced stores ----
    {
        const int c_ = tid & 255;
        const int dh = tid >> 8;                     // d half
        const int k  = kbx[c_];
        const float* qrow = embt + k * 64 + dh * 32; // 128B, L2-resident
        float* op = out + xslab + (size_t)(dh * 32) * 256 + c_;
        #pragma unroll
        for (int q4 = 0; q4 < 8; ++q4) {
            f32x4 qq = *reinterpret_cast<const f32x4*>(&qrow[q4 * 4]);
            #pragma unroll
            for (int j = 0; j < 4; ++j)
                op[(q4 * 4 + j) * 256] = qq[j];
        }
        if (tid < 256)
            outIdx[(size_t)(b * 256 + tid) * 16 + g] = (float)kbx[tid];
    }
}

// ---------------- fallback (ws too small): R5-style self-contained -------------
__global__ __launch_bounds__(512, 2)
void vq_fallback(const float* __restrict__ x, const float* __restrict__ meanp,
                 const float* __restrict__ sdp, const float* __restrict__ emb,
                 float* __restrict__ out, float* __restrict__ outIdx)
{
    __shared__ __align__(16) f16 xa[128 * 128];
    __shared__ __align__(16) f16 es2[128 * 128];
    __shared__ float e2s[512];
    __shared__ float red_v[4][128];
    __shared__ int   red_i[4][128];
    __shared__ int   kb[128];

    const int tid  = threadIdx.x;
    const int lane = tid & 63;
    const int wid  = tid >> 6;
    const int wr   = wid >> 2;
    const int wc   = wid & 3;
    const int lr   = lane & 15;
    const int lk   = lane >> 4;

    const int blk   = blockIdx.x;
    const int chalf = blk & 1;
    const int g     = (blk >> 1) & 15;
    const int b     = blk >> 5;

    const float mean = meanp[0];
    const float sd   = sdp[0];
    const bool  sdz  = (sd == 0.0f);
    const float safe = sdz ? 1.0f : sd;

    const int xbase = b * 262144 + g * 16384 + chalf * 128;

    {
        const int c_ = tid & 127;
        const int dq = tid >> 7;
        const float* src = x + xbase + c_;
        #pragma unroll
        for (int jv = 0; jv < 2; ++jv) {
            f16x8 hi, lo;
            #pragma unroll
            for (int e = 0; e < 8; ++e) {
                int d = dq * 16 + jv * 8 + e;
                float v = src[d * 256];
                float s = (sdz ? 0.0f : v / safe) - mean;
                f16 h = (f16)s;
                hi[e] = h;
                lo[e] = (f16)(s - (float)h);
            }
            *reinterpret_cast<f16x8*>(&xa[swz(c_, dq * 16 + jv * 8)])      = hi;
            *reinterpret_cast<f16x8*>(&xa[swz(c_, 64 + dq * 16 + jv * 8)]) = lo;
        }
    }
    {
        float s = 0.0f;
        for (int d = 0; d < 64; ++d) {
            float v = emb[d * 512 + tid];
            s = fmaf(v, v, s);
        }
        e2s[tid] = s;
    }

    float bestv[16];
    int   besti[16];
    #pragma unroll
    for (int s = 0; s < 16; ++s) { bestv[s] = FLTMAX; besti[s] = 0; }

    for (int ch = 0; ch < 4; ++ch) {
        __syncthreads();
        {
            const int cl = tid & 127;
            const int dq = tid >> 7;
            const float* srcE = emb + ch * 128 + cl;
            #pragma unroll
            for (int jv = 0; jv < 2; ++jv) {
                f16x8 hi, lo;
                #pragma unroll
                for (int e = 0; e < 8; ++e) {
                    int d = dq * 16 + jv * 8 + e;
                    float v = srcE[d * 512];
                    f16 h = (f16)v;
                    hi[e] = h;
                    lo[e] = (f16)(v - (float)h);
                }
                *reinterpret_cast<f16x8*>(&es2[swz(cl, dq * 16 + jv * 8)])      = hi;
                *reinterpret_cast<f16x8*>(&es2[swz(cl, 64 + dq * 16 + jv * 8)]) = lo;
            }
        }
        __syncthreads();

        f32x4 acc[4][2];
        #pragma unroll
        for (int fi = 0; fi < 4; ++fi)
            #pragma unroll
            for (int fj = 0; fj < 2; ++fj)
                acc[fi][fj] = (f32x4){0.f, 0.f, 0.f, 0.f};

        #pragma unroll
        for (int t = 0; t < 3; ++t) {
            const int ah2 = (t == 2) ? 1 : 0;
            const int eh2 = (t == 1) ? 1 : 0;
            #pragma unroll
            for (int dh2 = 0; dh2 < 2; ++dh2) {
                const int kB = eh2 * 64 + dh2 * 32 + lk * 8;
                const int kA = ah2 * 64 + dh2 * 32 + lk * 8;
                f16x8 bf[2], af[4];
                #pragma unroll
                for (int fj = 0; fj < 2; ++fj)
                    bf[fj] = *reinterpret_cast<const f16x8*>(
                        &es2[swz(wc * 32 + fj * 16 + lr, kB)]);
                #pragma unroll
                for (int fi = 0; fi < 4; ++fi)
                    af[fi] = *reinterpret_cast<const f16x8*>(
                        &xa[swz(wr * 64 + fi * 16 + lr, kA)]);
                #pragma unroll
                for (int fi = 0; fi < 4; ++fi)
                    #pragma unroll
                    for (int fj = 0; fj < 2; ++fj)
                        acc[fi][fj] = __builtin_amdgcn_mfma_f32_16x16x32_f16(
                            af[fi], bf[fj], acc[fi][fj], 0, 0, 0);
            }
        }

        #pragma unroll
        for (int fj = 0; fj < 2; ++fj) {
            const int codeg = ch * 128 + wc * 32 + fj * 16 + lr;
            const float e2v = e2s[codeg];
            #pragma unroll
            for (int fi = 0; fi < 4; ++fi)
                #pragma unroll
                for (int r = 0; r < 4; ++r) {
                    float vd = fmaf(-2.0f, acc[fi][fj][r], e2v);
                    const int s = fi * 4 + r;
                    if (vd < bestv[s]) { bestv[s] = vd; besti[s] = codeg; }
                }
        }
    }

    #pragma unroll
    for (int s = 0; s < 16; ++s) {
        float v = bestv[s]; int i = besti[s];
        #pragma unroll
        for (int m = 1; m < 16; m <<= 1) {
            float v2 = __shfl_xor(v, m, 64);
            int   i2 = __shfl_xor(i, m, 64);
            if (v2 < v || (v2 == v && i2 < i)) { v = v2; i = i2; }
        }
        bestv[s] = v; besti[s] = i;
    }
    if (lr == 0) {
        #pragma unroll
        for (int fi = 0; fi < 4; ++fi)
            #pragma unroll
            for (int r = 0; r < 4; ++r) {
                int row = wr * 64 + fi * 16 + lk * 4 + r;
                red_v[wc][row] = bestv[fi * 4 + r];
                red_i[wc][row] = besti[fi * 4 + r];
            }
    }
    __syncthreads();
    if (tid < 128) {
        float bv = red_v[0][tid]; int bi = red_i[0][tid];
        #pragma unroll
        for (int w = 1; w < 4; ++w) {
            float v = red_v[w][tid]; int i = red_i[w][tid];
            if (v < bv || (v == bv && i < bi)) { bv = v; bi = i; }
        }
        kb[tid] = bi;
    }
    __syncthreads();

    float* out_ = out + xbase;
    #pragma unroll 4
    for (int i = 0; i < 16; ++i) {
        int lin = i * 512 + tid;
        int c_  = lin & 127;
        int d   = lin >> 7;
        float q = emb[d * 512 + kb[c_]];
        out_[d * 256 + c_] = (q + mean) * sd;
    }
    if (tid < 128) {
        int n = (b * 256 + chalf * 128 + tid) * 16 + g;
        outIdx[n] = (float)kb[tid];
    }
}

extern "C" void kernel_launch(void* const* d_in, const int* in_sizes, int n_in,
                              void* d_out, int out_size, void* d_ws, size_t ws_size,
                              hipStream_t stream) {
    const float* x    = (const float*)d_in[0];
    const float* mean = (const float*)d_in[1];
    const float* sd   = (const float*)d_in[2];
    const float* emb  = (const float*)d_in[3];
    float* out    = (float*)d_out;
    float* outIdx = out + NELEM0;

    if (ws_size >= (size_t)WS_NEED) {
        f16*   ecvt = (f16*)d_ws;
        float* e2p  = (float*)((char*)d_ws + 131072);
        float* embt = (float*)((char*)d_ws + 139264);
        prep_kernel<<<dim3(8), dim3(256), 0, stream>>>(emb, mean, sd, ecvt, e2p, embt);
        vq_main<<<dim3(512), dim3(512), 0, stream>>>(x, mean, sd, ecvt, e2p, embt, out, outIdx);
    } else {
        vq_fallback<<<dim3(1024), dim3(512), 0, stream>>>(x, mean, sd, emb, out, outIdx);
    }
}

// Round 10
// 45.520 us; speedup vs baseline: 2.2379x; 1.5259x over previous
//
#include <hip/hip_runtime.h>

// VectorQuantiser R10: R9's contiguous/LDS-fed inner loop at 4x the occupancy.
// LDS 133KB->35KB (A-frags in regs, es chunks 64 codes double-buffered 2x16KB)
// -> 4 blocks/CU; launch_bounds(256,4) with live-set ~100 -> 4 waves/SIMD.
// prep: ecvt f16-split PRE-SWIZZLED codebook [512][128]; e2 partials; embt affine.
// dist = e2[k] - 2*(xh.eh + xh.el + xl.eh); argmin fully in-wave.

typedef _Float16 f16;
typedef _Float16 f16x8 __attribute__((ext_vector_type(8)));
typedef float    f32x4 __attribute__((ext_vector_type(4)));

#define NELEM0 8388608
#define FLTMAX 3.402823466e38f
// ws: [0,131072) ecvt_sw f16[512][128]; [131072,139264) e2p f32[4][512];
//     [139264,270336) embt f32[512][64]
#define WS_NEED 270336

// LDS read swizzle: f16 index = row*128 + (koff ^ ((row&7)<<3))
__device__ __forceinline__ int swz(int row, int koff) {
    return row * 128 + (koff ^ ((row & 7) << 3));
}

// prep: 8 blocks x 256 thr. block = (code-half)<<2 | d-chunk.
__global__ void prep_kernel(const float* __restrict__ emb, const float* __restrict__ meanp,
                            const float* __restrict__ sdp, f16* __restrict__ ecvt,
                            float* __restrict__ e2p, float* __restrict__ embt) {
    const int code = (blockIdx.x >> 2) * 256 + threadIdx.x;
    const int dc   = blockIdx.x & 3;                 // 16 d's per block
    const float mean = meanp[0];
    const float sd   = sdp[0];
    float s = 0.0f;
    #pragma unroll
    for (int j = 0; j < 16; ++j) {
        const int d = dc * 16 + j;
        float v = emb[d * 512 + code];               // coalesced across codes
        s = fmaf(v, v, s);
        f16 h = (f16)v;
        f16 l = (f16)(v - (float)h);
        const int gg = (d >> 3) ^ (code & 7);        // pre-apply inverse swizzle
        const int e  = d & 7;
        ecvt[code * 128 + gg * 8 + e]      = h;      // eh groups 0-7
        ecvt[code * 128 + 64 + gg * 8 + e] = l;      // el groups 8-15
        embt[code * 64 + d] = (v + mean) * sd;       // affine pre-applied
    }
    e2p[dc * 512 + code] = s;
}

__global__ __launch_bounds__(256, 4)
void vq_main(const float* __restrict__ x, const float* __restrict__ meanp,
             const float* __restrict__ sdp, const f16* __restrict__ ecvt,
             const float* __restrict__ e2p, const float* __restrict__ embt,
             float* __restrict__ out, float* __restrict__ outIdx)
{
    __shared__ __align__(16) f16 es[2][64 * 128];    // 2 x 16 KB, linear copies
    __shared__ float e2s[512];
    __shared__ int   kbs[128];

    const int tid  = threadIdx.x;
    const int lane = tid & 63;
    const int wid  = tid >> 6;       // 0..3; wave owns 32 rows
    const int lr   = lane & 15;
    const int lk   = lane >> 4;

    const int blk   = blockIdx.x;    // 1024 = 32 b x 16 g x 2 chalf
    const int chalf = blk & 1;
    const int g     = (blk >> 1) & 15;
    const int b     = blk >> 5;

    const float sd   = sdp[0];
    const bool  sdz  = (sd == 0.0f);
    const float sinv = sdz ? 0.0f : (1.0f / sd);
    const float mean = meanp[0];

    const size_t xslab = (size_t)b * 262144 + (size_t)g * 16384;
    const int c0 = chalf * 128 + wid * 32;           // wave's first row (global c)

    // ---- A fragments: 32 rows/wave straight from global into regs ----
    f16x8 ah[2][2], al[2][2];        // [set][ks: d 0-31 / 32-63]
    #pragma unroll
    for (int s = 0; s < 2; ++s) {
        const float* rp = x + xslab + c0 + s * 16 + lr;
        #pragma unroll
        for (int ks = 0; ks < 2; ++ks)
            #pragma unroll
            for (int j = 0; j < 8; ++j) {
                float v  = rp[(ks * 32 + lk * 8 + j) * 256];
                float sv = fmaf(v, sinv, -mean);
                f16 h = (f16)sv;
                ah[s][ks][j] = h;
                al[s][ks][j] = (f16)(sv - (float)h);
            }
    }

    // ---- e2 sums (fixed dc order: deterministic) ----
    e2s[tid]       = ((e2p[tid]       + e2p[512 + tid])       + e2p[1024 + tid])       + e2p[1536 + tid];
    // second half
    e2s[256 + tid] = 0.0f; // placeholder overwritten below (keeps single-pass simple)
    {
        const int t2 = 256 + tid;
        e2s[t2] = ((e2p[t2] + e2p[512 + t2]) + e2p[1024 + t2]) + e2p[1536 + t2];
    }

    // ---- prologue: stage chunk 0 (contiguous: wave covers 1KB/instr) ----
    f16x8 pre[4];
    #pragma unroll
    for (int i = 0; i < 4; ++i)
        pre[i] = *reinterpret_cast<const f16x8*>(&ecvt[i * 2048 + tid * 8]);
    #pragma unroll
    for (int i = 0; i < 4; ++i)
        *reinterpret_cast<f16x8*>(&es[0][i * 2048 + tid * 8]) = pre[i];
    __syncthreads();

    float bestv[8];
    int   besti[8];
    #pragma unroll
    for (int s = 0; s < 8; ++s) { bestv[s] = FLTMAX; besti[s] = 0; }

    // ---- main loop: 8 chunks x 64 codes, T14 issue-early/write-late ----
    for (int ch = 0; ch < 8; ++ch) {
        const int cur = ch & 1;
        const f16* eb = &es[cur][0];

        if (ch < 7) {                                // issue next-chunk loads EARLY
            #pragma unroll
            for (int i = 0; i < 4; ++i)
                pre[i] = *reinterpret_cast<const f16x8*>(
                    &ecvt[(ch + 1) * 8192 + i * 2048 + tid * 8]);
        }

        #pragma unroll
        for (int cf = 0; cf < 4; ++cf) {             // 16 codes per cfrag
            const int rowB = cf * 16 + lr;
            f16x8 bh0 = *reinterpret_cast<const f16x8*>(&eb[swz(rowB, lk * 8)]);
            f16x8 bh1 = *reinterpret_cast<const f16x8*>(&eb[swz(rowB, 32 + lk * 8)]);
            f16x8 bl0 = *reinterpret_cast<const f16x8*>(&eb[swz(rowB, 64 + lk * 8)]);
            f16x8 bl1 = *reinterpret_cast<const f16x8*>(&eb[swz(rowB, 96 + lk * 8)]);
            const int codeg = ch * 64 + cf * 16 + lr;
            const float e2v = e2s[codeg];
            #pragma unroll
            for (int s = 0; s < 2; ++s) {
                f32x4 acc = (f32x4){0.f, 0.f, 0.f, 0.f};
                acc = __builtin_amdgcn_mfma_f32_16x16x32_f16(ah[s][0], bh0, acc, 0, 0, 0);
                acc = __builtin_amdgcn_mfma_f32_16x16x32_f16(ah[s][1], bh1, acc, 0, 0, 0);
                acc = __builtin_amdgcn_mfma_f32_16x16x32_f16(ah[s][0], bl0, acc, 0, 0, 0);
                acc = __builtin_amdgcn_mfma_f32_16x16x32_f16(ah[s][1], bl1, acc, 0, 0, 0);
                acc = __builtin_amdgcn_mfma_f32_16x16x32_f16(al[s][0], bh0, acc, 0, 0, 0);
                acc = __builtin_amdgcn_mfma_f32_16x16x32_f16(al[s][1], bh1, acc, 0, 0, 0);
                #pragma unroll
                for (int r = 0; r < 4; ++r) {
                    float vd = fmaf(-2.0f, acc[r], e2v);
                    const int si = s * 4 + r;
                    if (vd < bestv[si]) { bestv[si] = vd; besti[si] = codeg; }
                }
            }
        }

        if (ch < 7) {                                // write-late to other buffer
            #pragma unroll
            for (int i = 0; i < 4; ++i)
                *reinterpret_cast<f16x8*>(&es[cur ^ 1][i * 2048 + tid * 8]) = pre[i];
        }
        __syncthreads();
    }

    // ---- in-wave argmin reduce over the 16 code-columns ----
    #pragma unroll
    for (int si = 0; si < 8; ++si) {
        float v = bestv[si]; int i = besti[si];
        #pragma unroll
        for (int m = 1; m < 16; m <<= 1) {
            float v2 = __shfl_xor(v, m, 64);
            int   i2 = __shfl_xor(i, m, 64);
            if (v2 < v || (v2 == v && i2 < i)) { v = v2; i = i2; }
        }
        bestv[si] = v; besti[si] = i;
    }
    if (lr == 0) {
        #pragma unroll
        for (int s = 0; s < 2; ++s)
            #pragma unroll
            for (int r = 0; r < 4; ++r)
                kbs[wid * 32 + s * 16 + lk * 4 + r] = besti[s * 4 + r];  // C/D row map
    }
    __syncthreads();

    // ---- epilogue: scatter-read embt row, coalesced d-major stores ----
    {
        const int c_ = tid & 127;
        const int dh = tid >> 7;                     // d half (32 each)
        const int k  = kbs[c_];
        const float* qrow = embt + k * 64 + dh * 32; // L2-resident
        float* op = out + xslab + (size_t)(dh * 32) * 256 + chalf * 128 + c_;
        #pragma unroll
        for (int q4 = 0; q4 < 8; ++q4) {
            f32x4 qq = *reinterpret_cast<const f32x4*>(&qrow[q4 * 4]);
            #pragma unroll
            for (int j = 0; j < 4; ++j)
                op[(q4 * 4 + j) * 256] = qq[j];
        }
    }
    if (tid < 128)
        outIdx[(size_t)(b * 256 + chalf * 128 + tid) * 16 + g] = (float)kbs[tid];
}

// ---------------- fallback (ws too small): R5-style self-contained -------------
__global__ __launch_bounds__(512, 2)
void vq_fallback(const float* __restrict__ x, const float* __restrict__ meanp,
                 const float* __restrict__ sdp, const float* __restrict__ emb,
                 float* __restrict__ out, float* __restrict__ outIdx)
{
    __shared__ __align__(16) f16 xa[128 * 128];
    __shared__ __align__(16) f16 es2[128 * 128];
    __shared__ float e2s[512];
    __shared__ float red_v[4][128];
    __shared__ int   red_i[4][128];
    __shared__ int   kb[128];

    const int tid  = threadIdx.x;
    const int lane = tid & 63;
    const int wid  = tid >> 6;
    const int wr   = wid >> 2;
    const int wc   = wid & 3;
    const int lr   = lane & 15;
    const int lk   = lane >> 4;

    const int blk   = blockIdx.x;
    const int chalf = blk & 1;
    const int g     = (blk >> 1) & 15;
    const int b     = blk >> 5;

    const float mean = meanp[0];
    const float sd   = sdp[0];
    const bool  sdz  = (sd == 0.0f);
    const float safe = sdz ? 1.0f : sd;

    const int xbase = b * 262144 + g * 16384 + chalf * 128;

    {
        const int c_ = tid & 127;
        const int dq = tid >> 7;
        const float* src = x + xbase + c_;
        #pragma unroll
        for (int jv = 0; jv < 2; ++jv) {
            f16x8 hi, lo;
            #pragma unroll
            for (int e = 0; e < 8; ++e) {
                int d = dq * 16 + jv * 8 + e;
                float v = src[d * 256];
                float s = (sdz ? 0.0f : v / safe) - mean;
                f16 h = (f16)s;
                hi[e] = h;
                lo[e] = (f16)(s - (float)h);
            }
            *reinterpret_cast<f16x8*>(&xa[swz(c_, dq * 16 + jv * 8)])      = hi;
            *reinterpret_cast<f16x8*>(&xa[swz(c_, 64 + dq * 16 + jv * 8)]) = lo;
        }
    }
    {
        float s = 0.0f;
        for (int d = 0; d < 64; ++d) {
            float v = emb[d * 512 + tid];
            s = fmaf(v, v, s);
        }
        e2s[tid] = s;
    }

    float bestv[16];
    int   besti[16];
    #pragma unroll
    for (int s = 0; s < 16; ++s) { bestv[s] = FLTMAX; besti[s] = 0; }

    for (int ch = 0; ch < 4; ++ch) {
        __syncthreads();
        {
            const int cl = tid & 127;
            const int dq = tid >> 7;
            const float* srcE = emb + ch * 128 + cl;
            #pragma unroll
            for (int jv = 0; jv < 2; ++jv) {
                f16x8 hi, lo;
                #pragma unroll
                for (int e = 0; e < 8; ++e) {
                    int d = dq * 16 + jv * 8 + e;
                    float v = srcE[d * 512];
                    f16 h = (f16)v;
                    hi[e] = h;
                    lo[e] = (f16)(v - (float)h);
                }
                *reinterpret_cast<f16x8*>(&es2[swz(cl, dq * 16 + jv * 8)])      = hi;
                *reinterpret_cast<f16x8*>(&es2[swz(cl, 64 + dq * 16 + jv * 8)]) = lo;
            }
        }
        __syncthreads();

        f32x4 acc[4][2];
        #pragma unroll
        for (int fi = 0; fi < 4; ++fi)
            #pragma unroll
            for (int fj = 0; fj < 2; ++fj)
                acc[fi][fj] = (f32x4){0.f, 0.f, 0.f, 0.f};

        #pragma unroll
        for (int t = 0; t < 3; ++t) {
            const int ah2 = (t == 2) ? 1 : 0;
            const int eh2 = (t == 1) ? 1 : 0;
            #pragma unroll
            for (int dh2 = 0; dh2 < 2; ++dh2) {
                const int kB = eh2 * 64 + dh2 * 32 + lk * 8;
                const int kA = ah2 * 64 + dh2 * 32 + lk * 8;
                f16x8 bf[2], af[4];
                #pragma unroll
                for (int fj = 0; fj < 2; ++fj)
                    bf[fj] = *reinterpret_cast<const f16x8*>(
                        &es2[swz(wc * 32 + fj * 16 + lr, kB)]);
                #pragma unroll
                for (int fi = 0; fi < 4; ++fi)
                    af[fi] = *reinterpret_cast<const f16x8*>(
                        &xa[swz(wr * 64 + fi * 16 + lr, kA)]);
                #pragma unroll
                for (int fi = 0; fi < 4; ++fi)
                    #pragma unroll
                    for (int fj = 0; fj < 2; ++fj)
                        acc[fi][fj] = __builtin_amdgcn_mfma_f32_16x16x32_f16(
                            af[fi], bf[fj], acc[fi][fj], 0, 0, 0);
            }
        }

        #pragma unroll
        for (int fj = 0; fj < 2; ++fj) {
            const int codeg = ch * 128 + wc * 32 + fj * 16 + lr;
            const float e2v = e2s[codeg];
            #pragma unroll
            for (int fi = 0; fi < 4; ++fi)
                #pragma unroll
                for (int r = 0; r < 4; ++r) {
                    float vd = fmaf(-2.0f, acc[fi][fj][r], e2v);
                    const int s = fi * 4 + r;
                    if (vd < bestv[s]) { bestv[s] = vd; besti[s] = codeg; }
                }
        }
    }

    #pragma unroll
    for (int s = 0; s < 16; ++s) {
        float v = bestv[s]; int i = besti[s];
        #pragma unroll
        for (int m = 1; m < 16; m <<= 1) {
            float v2 = __shfl_xor(v, m, 64);
            int   i2 = __shfl_xor(i, m, 64);
            if (v2 < v || (v2 == v && i2 < i)) { v = v2; i = i2; }
        }
        bestv[s] = v; besti[s] = i;
    }
    if (lr == 0) {
        #pragma unroll
        for (int fi = 0; fi < 4; ++fi)
            #pragma unroll
            for (int r = 0; r < 4; ++r) {
                int row = wr * 64 + fi * 16 + lk * 4 + r;
                red_v[wc][row] = bestv[fi * 4 + r];
                red_i[wc][row] = besti[fi * 4 + r];
            }
    }
    __syncthreads();
    if (tid < 128) {
        float bv = red_v[0][tid]; int bi = red_i[0][tid];
        #pragma unroll
        for (int w = 1; w < 4; ++w) {
            float v = red_v[w][tid]; int i = red_i[w][tid];
            if (v < bv || (v == bv && i < bi)) { bv = v; bi = i; }
        }
        kb[tid] = bi;
    }
    __syncthreads();

    float* out_ = out + xbase;
    #pragma unroll 4
    for (int i = 0; i < 16; ++i) {
        int lin = i * 512 + tid;
        int c_  = lin & 127;
        int d   = lin >> 7;
        float q = emb[d * 512 + kb[c_]];
        out_[d * 256 + c_] = (q + mean) * sd;
    }
    if (tid < 128) {
        int n = (b * 256 + chalf * 128 + tid) * 16 + g;
        outIdx[n] = (float)kb[tid];
    }
}

extern "C" void kernel_launch(void* const* d_in, const int* in_sizes, int n_in,
                              void* d_out, int out_size, void* d_ws, size_t ws_size,
                              hipStream_t stream) {
    const float* x    = (const float*)d_in[0];
    const float* mean = (const float*)d_in[1];
    const float* sd   = (const float*)d_in[2];
    const float* emb  = (const float*)d_in[3];
    float* out    = (float*)d_out;
    float* outIdx = out + NELEM0;

    if (ws_size >= (size_t)WS_NEED) {
        f16*   ecvt = (f16*)d_ws;
        float* e2p  = (float*)((char*)d_ws + 131072);
        float* embt = (float*)((char*)d_ws + 139264);
        prep_kernel<<<dim3(8), dim3(256), 0, stream>>>(emb, mean, sd, ecvt, e2p, embt);
        vq_main<<<dim3(1024), dim3(256), 0, stream>>>(x, mean, sd, ecvt, e2p, embt, out, outIdx);
    } else {
        vq_fallback<<<dim3(1024), dim3(512), 0, stream>>>(x, mean, sd, emb, out, outIdx);
    }
}